// Round 2
// baseline (397.763 us; speedup 1.0000x reference)
//
#include <hip/hip_runtime.h>
#include <stdint.h>

typedef __attribute__((ext_vector_type(4))) float f32x4;
typedef __attribute__((ext_vector_type(8))) short s16x8;
typedef float f32x4u __attribute__((ext_vector_type(4), aligned(4)));
typedef unsigned short u16x4 __attribute__((ext_vector_type(4)));

struct Params {
  const float* cls_feat[3];
  const float* reg_feat[3];
  const float* obj_w[3];
  const float* obj_b[3];
  const float* cls_w[3];
  const float* cls_b[3];
  const float* reg_w[3];
  const float* reg_b[3];
  unsigned short* wbf;   // d_ws: packed bf16 weights [kind][level][80][256]
  float* out;
};

__device__ __forceinline__ unsigned short f2bf(float f) {
  unsigned int u = __builtin_bit_cast(unsigned int, f);
  u = (u + 0x7FFFu + ((u >> 16) & 1u)) >> 16;  // RNE
  return (unsigned short)u;
}

// ---- prep: fp32 weights -> bf16 packed rows in d_ws --------------------------
// 480 rows: kind(2) x level(3) x o(80). reg kind: rows 0..63 = reg_w,
// row 64 = obj_w, rows 65..79 = 0. 64 threads x 4 k each.
__global__ __launch_bounds__(64) void prep_weights(Params p) {
  const int R = blockIdx.x;            // 0..479
  const int kind  = R / 240;
  const int rem   = R - kind * 240;
  const int level = rem / 80;
  const int o     = rem - level * 80;
  const float* src = nullptr;
  if (kind == 0)      src = p.cls_w[level] + (size_t)o * 256;
  else if (o < 64)    src = p.reg_w[level] + (size_t)o * 256;
  else if (o == 64)   src = p.obj_w[level];
  unsigned short* dst = p.wbf + (size_t)R * 256 + threadIdx.x * 4;
  u16x4 h = {0, 0, 0, 0};
  if (src) {
    f32x4 f = *(const f32x4u*)(src + threadIdx.x * 4);
    h[0] = f2bf(f[0]); h[1] = f2bf(f[1]); h[2] = f2bf(f[2]); h[3] = f2bf(f[3]);
  }
  *(u16x4*)dst = h;
}

// ---- main: one wave = one 16-m tile, full K=256 in registers, 5 o-tiles -----
__global__ __launch_bounds__(256) void head_kernel(Params p) {
  const int tid  = threadIdx.x;
  const int lane = tid & 63;
  const int wave = tid >> 6;
  const int quad = lane >> 4;
  const int col  = lane & 15;
  const int kind = blockIdx.y;         // 0 = cls, 1 = reg/obj

  // wave-task: 525 m-tiles of 16 per batch (400 + 100 + 25, all exact)
  const int t = blockIdx.x * 4 + wave; // 0..8399
  const int b = t / 525;
  const int r = t - b * 525;
  int level, m0;
  if (r < 400)      { level = 0; m0 = r * 16; }
  else if (r < 500) { level = 1; m0 = (r - 400) * 16; }
  else              { level = 2; m0 = (r - 500) * 16; }

  const int   LM_[3]   = {6400, 1600, 400};
  const int   LW_[3]   = {80, 40, 20};
  const float LS_[3]   = {8.f, 16.f, 32.f};
  const int   LOFF_[3] = {0, 6400, 8000};
  const int   Mlvl = LM_[level];
  const float strd = LS_[level];

  // ---- B-fragments straight from global: F[k][m], k = s*32 + quad*8 + j ----
  const float* feat = (kind ? p.reg_feat[level] : p.cls_feat[level])
                      + (size_t)b * 256 * (size_t)Mlvl + m0 + col;
  s16x8 bfrag[8];
  #pragma unroll
  for (int s = 0; s < 8; ++s) {
    float f[8];
    #pragma unroll
    for (int j = 0; j < 8; ++j)
      f[j] = feat[(size_t)(s * 32 + quad * 8 + j) * Mlvl];
    s16x8 h;
    #pragma unroll
    for (int j = 0; j < 8; ++j) h[j] = (short)f2bf(f[j]);
    bfrag[s] = h;
  }

  const unsigned short* wbase = p.wbf + (size_t)((kind * 3 + level) * 80) * 256;
  const size_t outbase = (size_t)b * 8400 + LOFF_[level] + m0;
  float* out = p.out;
  const size_t rowoff = (outbase + col) * 149;

  float g[4];  // DFL expectations (reg path)

  #pragma unroll
  for (int tile = 0; tile < 5; ++tile) {
    const unsigned short* wp = wbase + (size_t)(tile * 16 + col) * 256 + quad * 8;
    f32x4 d = {0.f, 0.f, 0.f, 0.f};
    #pragma unroll
    for (int s = 0; s < 8; ++s) {
      s16x8 a = *(const s16x8*)(wp + s * 32);
      d = __builtin_amdgcn_mfma_f32_16x16x32_bf16(a, bfrag[s], d, 0, 0, 0);
    }

    if (kind == 0) {
      // cls logits: channels 1 + (tile*16 + quad*4 + r)
      f32x4 bias = *(const f32x4u*)(p.cls_b[level] + tile * 16 + quad * 4);
      f32x4 v = d + bias;
      *(f32x4u*)(out + rowoff + 1 + tile * 16 + quad * 4) = v;
    } else if (tile < 4) {
      // reg logits: channels 81 + (tile*16 + quad*4 + r); DFL group = tile
      f32x4 bias = *(const f32x4u*)(p.reg_b[level] + tile * 16 + quad * 4);
      f32x4 v = d + bias;
      *(f32x4u*)(out + rowoff + 81 + tile * 16 + quad * 4) = v;
      // softmax over 16 bins (4 regs x 4 quads, same m = col)
      float mx = fmaxf(fmaxf(v[0], v[1]), fmaxf(v[2], v[3]));
      mx = fmaxf(mx, __shfl_xor(mx, 16, 64));
      mx = fmaxf(mx, __shfl_xor(mx, 32, 64));
      const float e0 = __expf(v[0] - mx), e1 = __expf(v[1] - mx);
      const float e2 = __expf(v[2] - mx), e3 = __expf(v[3] - mx);
      float s = e0 + e1 + e2 + e3;
      const float q4 = (float)(quad * 4);
      float n = q4 * e0 + (q4 + 1.f) * e1 + (q4 + 2.f) * e2 + (q4 + 3.f) * e3;
      s += __shfl_xor(s, 16, 64); s += __shfl_xor(s, 32, 64);
      n += __shfl_xor(n, 16, 64); n += __shfl_xor(n, 32, 64);
      g[tile] = (16.f / 15.f) * n / s;   // all lanes hold the result
    } else {
      // obj: packed row 64 -> quad 0, reg 0, channel 0
      if (quad == 0) out[rowoff] = d[0] + p.obj_b[level][0];
    }
  }

  // box decode (reg path): channels 145..148
  if (kind == 1 && quad == 1) {
    const int mg = m0 + col;
    const int hh = mg / LW_[level];
    const int ww = mg - hh * LW_[level];
    const float ax = (ww + 0.5f) * strd;
    const float ay = (hh + 0.5f) * strd;
    f32x4 box;
    box[0] = ax - g[0] * strd;
    box[1] = ay - g[1] * strd;
    box[2] = ax + g[2] * strd;
    box[3] = ay + g[3] * strd;
    *(f32x4u*)(out + rowoff + 145) = box;
  }
}

extern "C" void kernel_launch(void* const* d_in, const int* in_sizes, int n_in,
                              void* d_out, int out_size, void* d_ws, size_t ws_size,
                              hipStream_t stream) {
  (void)in_sizes; (void)n_in; (void)out_size; (void)ws_size;
  Params p;
  p.cls_feat[0] = (const float*)d_in[0];
  p.reg_feat[0] = (const float*)d_in[1];
  p.cls_feat[1] = (const float*)d_in[2];
  p.reg_feat[1] = (const float*)d_in[3];
  p.cls_feat[2] = (const float*)d_in[4];
  p.reg_feat[2] = (const float*)d_in[5];
  for (int l = 0; l < 3; ++l) {
    const int base = 6 + l * 6;
    p.obj_w[l] = (const float*)d_in[base + 0];
    p.obj_b[l] = (const float*)d_in[base + 1];
    p.cls_w[l] = (const float*)d_in[base + 2];
    p.cls_b[l] = (const float*)d_in[base + 3];
    p.reg_w[l] = (const float*)d_in[base + 4];
    p.reg_b[l] = (const float*)d_in[base + 5];
  }
  p.wbf = (unsigned short*)d_ws;  // needs 480*256*2 = 245760 B
  p.out = (float*)d_out;

  hipLaunchKernelGGL(prep_weights, dim3(480), dim3(64), 0, stream, p);
  // 8400 wave-tasks per kind, 4 waves/block -> 2100 blocks; y: 0=cls, 1=reg
  hipLaunchKernelGGL(head_kernel, dim3(2100, 2), dim3(256), 0, stream, p);
}

// Round 3
// 385.019 us; speedup vs baseline: 1.0331x; 1.0331x over previous
//
#include <hip/hip_runtime.h>
#include <stdint.h>

typedef __attribute__((ext_vector_type(4))) float f32x4;
typedef __attribute__((ext_vector_type(8))) short s16x8;
typedef float f32x4u __attribute__((ext_vector_type(4), aligned(4)));
typedef unsigned short u16x4 __attribute__((ext_vector_type(4)));

struct Params {
  const float* cls_feat[3];
  const float* reg_feat[3];
  const float* obj_w[3];
  const float* obj_b[3];
  const float* cls_w[3];
  const float* cls_b[3];
  const float* reg_w[3];
  const float* reg_b[3];
  unsigned short* wbf;   // d_ws: packed bf16 weights [kind][level][80][256]
  float* out;
};

__device__ __forceinline__ unsigned short f2bf(float f) {
  unsigned int u = __builtin_bit_cast(unsigned int, f);
  u = (u + 0x7FFFu + ((u >> 16) & 1u)) >> 16;  // RNE
  return (unsigned short)u;
}

// ---- prep: fp32 weights -> bf16 packed rows in d_ws -------------------------
__global__ __launch_bounds__(64) void prep_weights(Params p) {
  const int R = blockIdx.x;            // 0..479: kind(2) x level(3) x o(80)
  const int kind  = R / 240;
  const int rem   = R - kind * 240;
  const int level = rem / 80;
  const int o     = rem - level * 80;
  const float* src = nullptr;
  if (kind == 0)      src = p.cls_w[level] + (size_t)o * 256;
  else if (o < 64)    src = p.reg_w[level] + (size_t)o * 256;
  else if (o == 64)   src = p.obj_w[level];
  unsigned short* dst = p.wbf + (size_t)R * 256 + threadIdx.x * 4;
  u16x4 h = {0, 0, 0, 0};
  if (src) {
    f32x4 f = *(const f32x4u*)(src + threadIdx.x * 4);
    h[0] = f2bf(f[0]); h[1] = f2bf(f[1]); h[2] = f2bf(f[2]); h[3] = f2bf(f[3]);
  }
  *(u16x4*)dst = h;
}

#define SP 156  // sout pitch (dwords): %8==4 -> 2-way-max LDS banks; keeps 16B align

// ---- main: block = 64-m tile, waves 0-3 cls / 4-7 reg, LDS-staged output ----
__global__ __launch_bounds__(512, 4) void head_kernel(Params p) {
  const int tid  = threadIdx.x;
  const int lane = tid & 63;
  const int wave = tid >> 6;       // 0..7
  const int quad = lane >> 4;
  const int col  = lane & 15;
  const int kind = wave >> 2;      // 0 = cls, 1 = reg/obj
  const int msub = wave & 3;       // 16-m subtile within the 64-m tile

  // block -> (batch, level, 64-m tile). 132 tiles/batch: 100 + 25 + 7(last partial)
  const int bx = blockIdx.x;
  const int b  = bx / 132;
  const int t  = bx - b * 132;
  int level, tloc;
  if (t < 100)      { level = 0; tloc = t; }
  else if (t < 125) { level = 1; tloc = t - 100; }
  else              { level = 2; tloc = t - 125; }

  const int   Mlvl = (level == 0) ? 6400 : (level == 1) ? 1600 : 400;
  const int   Moff = (level == 0) ? 0    : (level == 1) ? 6400 : 8000;
  const float strd = (level == 0) ? 8.f  : (level == 1) ? 16.f : 32.f;

  const int m0t = tloc * 64;
  const int m0  = m0t + msub * 16;
  int valid = Mlvl - m0t; if (valid > 64) valid = 64;

  __shared__ float sout[64 * SP];  // 39936 B; channel c lives at [m][c+3]

  // ---- phase 1: feature B-fragments, 32-deep load batches ----
  const float* featb = (kind ? p.reg_feat[level] : p.cls_feat[level])
                       + (size_t)b * 256 * (size_t)Mlvl;
  int mg = m0 + col; if (mg > Mlvl - 1) mg = Mlvl - 1;  // clamp (partial tile / OOB)
  const float* fp = featb + mg + (size_t)(quad * 8) * Mlvl;

  s16x8 bfrag[8];
  #pragma unroll
  for (int half = 0; half < 2; ++half) {
    float f[4][8];
    #pragma unroll
    for (int s = 0; s < 4; ++s) {
      #pragma unroll
      for (int j = 0; j < 8; ++j)
        f[s][j] = fp[(size_t)((half * 4 + s) * 32 + j) * Mlvl];
    }
    #pragma unroll
    for (int s = 0; s < 4; ++s) {
      s16x8 h;
      #pragma unroll
      for (int j = 0; j < 8; ++j) h[j] = (short)f2bf(f[s][j]);
      bfrag[half * 4 + s] = h;
    }
  }

  // ---- phase 2: 5 o-tiles of MFMA + epilogue into LDS ----
  const unsigned short* wbase = p.wbf + (size_t)((kind * 3 + level) * 80) * 256;
  float* srow = &sout[(msub * 16 + col) * SP];
  float g[4];

  #pragma unroll
  for (int tile = 0; tile < 5; ++tile) {
    const unsigned short* wp = wbase + (size_t)(tile * 16 + col) * 256 + quad * 8;
    f32x4 d = {0.f, 0.f, 0.f, 0.f};
    #pragma unroll
    for (int s = 0; s < 8; ++s) {
      s16x8 a = *(const s16x8*)(wp + s * 32);
      d = __builtin_amdgcn_mfma_f32_16x16x32_bf16(a, bfrag[s], d, 0, 0, 0);
    }

    if (kind == 0) {
      f32x4 bias = *(const f32x4u*)(p.cls_b[level] + tile * 16 + quad * 4);
      *(f32x4*)(srow + 4 + tile * 16 + quad * 4) = d + bias;        // c = 1..80
    } else if (tile < 4) {
      f32x4 bias = *(const f32x4u*)(p.reg_b[level] + tile * 16 + quad * 4);
      f32x4 v = d + bias;
      *(f32x4*)(srow + 84 + tile * 16 + quad * 4) = v;              // c = 81..144
      // DFL softmax over 16 bins (4 regs x 4 quads, same m = col)
      float mx = fmaxf(fmaxf(v[0], v[1]), fmaxf(v[2], v[3]));
      mx = fmaxf(mx, __shfl_xor(mx, 16, 64));
      mx = fmaxf(mx, __shfl_xor(mx, 32, 64));
      const float e0 = __expf(v[0] - mx), e1 = __expf(v[1] - mx);
      const float e2 = __expf(v[2] - mx), e3 = __expf(v[3] - mx);
      float sden = e0 + e1 + e2 + e3;
      const float q4 = (float)(quad * 4);
      float num = q4 * e0 + (q4 + 1.f) * e1 + (q4 + 2.f) * e2 + (q4 + 3.f) * e3;
      sden += __shfl_xor(sden, 16, 64); sden += __shfl_xor(sden, 32, 64);
      num  += __shfl_xor(num, 16, 64);  num  += __shfl_xor(num, 32, 64);
      g[tile] = (16.f / 15.f) * num / sden;
    } else {
      if (quad == 0) srow[3] = d[0] + p.obj_b[level][0];            // c = 0 (obj)
    }
  }

  if (kind == 1) {
    // box decode: c = 145..148 (all quads hold g; quad 1 writes)
    const int LW = (level == 0) ? 80 : (level == 1) ? 40 : 20;
    const int hh = (level == 0) ? mg / 80 : (level == 1) ? mg / 40 : mg / 20;
    const int ww = mg - hh * LW;
    const float ax = (ww + 0.5f) * strd;
    const float ay = (hh + 0.5f) * strd;
    if (quad == 1) {
      f32x4 box;
      box[0] = ax - g[0] * strd;
      box[1] = ay - g[1] * strd;
      box[2] = ax + g[2] * strd;
      box[3] = ay + g[3] * strd;
      *(f32x4*)(srow + 148) = box;
    }
  }

  __syncthreads();

  // ---- phase 3: contiguous coalesced stream of complete 149-ch rows ----
  float* outp = p.out + ((size_t)b * 8400 + Moff + m0t) * 149;
  const int ndw = valid * 149;
  for (int i = tid; i < ndw; i += 512) {
    const int m = i / 149;        // constant divisor -> magic mul
    const int c = i - m * 149;
    outp[i] = sout[m * SP + c + 3];
  }
}

extern "C" void kernel_launch(void* const* d_in, const int* in_sizes, int n_in,
                              void* d_out, int out_size, void* d_ws, size_t ws_size,
                              hipStream_t stream) {
  (void)in_sizes; (void)n_in; (void)out_size; (void)ws_size;
  Params p;
  p.cls_feat[0] = (const float*)d_in[0];
  p.reg_feat[0] = (const float*)d_in[1];
  p.cls_feat[1] = (const float*)d_in[2];
  p.reg_feat[1] = (const float*)d_in[3];
  p.cls_feat[2] = (const float*)d_in[4];
  p.reg_feat[2] = (const float*)d_in[5];
  for (int l = 0; l < 3; ++l) {
    const int base = 6 + l * 6;
    p.obj_w[l] = (const float*)d_in[base + 0];
    p.obj_b[l] = (const float*)d_in[base + 1];
    p.cls_w[l] = (const float*)d_in[base + 2];
    p.cls_b[l] = (const float*)d_in[base + 3];
    p.reg_w[l] = (const float*)d_in[base + 4];
    p.reg_b[l] = (const float*)d_in[base + 5];
  }
  p.wbf = (unsigned short*)d_ws;  // needs 480*256*2 = 245760 B
  p.out = (float*)d_out;

  hipLaunchKernelGGL(prep_weights, dim3(480), dim3(64), 0, stream, p);
  hipLaunchKernelGGL(head_kernel, dim3(16 * 132), dim3(512), 0, stream, p);
}